// Round 1
// baseline (231.840 us; speedup 1.0000x reference)
//
#include <hip/hip_runtime.h>
#include <hip/hip_bf16.h>
#include <cmath>

// Problem constants (from reference)
#define N_TOK 32768
#define KDIM  1024
#define ODIM  1024

// GEMM tile config: 128x128 block, BK=64, 4 waves (2x2), wave tile 64x64 dual
#define BM 128
#define BN 128
#define BK 64
#define NKT (KDIM / BK)   // 16 k-tiles

typedef float          f32x4  __attribute__((ext_vector_type(4)));
typedef __bf16         bf16x8 __attribute__((ext_vector_type(8)));
typedef unsigned short us8    __attribute__((ext_vector_type(8)));
typedef unsigned short us4    __attribute__((ext_vector_type(4)));
typedef unsigned short us2    __attribute__((ext_vector_type(2)));

// round-to-nearest-even f32 -> bf16 (inputs are finite, no NaN handling needed)
static __device__ __forceinline__ unsigned short f2bf(float f) {
  unsigned u = __builtin_bit_cast(unsigned, f);
  u += 0x7FFFu + ((u >> 16) & 1u);
  return (unsigned short)(u >> 16);
}

static __device__ __forceinline__ f32x4 mfma16(us8 a, us8 b, f32x4 c) {
  return __builtin_amdgcn_mfma_f32_16x16x32_bf16(
      __builtin_bit_cast(bf16x8, a), __builtin_bit_cast(bf16x8, b), c, 0, 0, 0);
}

static __device__ __forceinline__ void gl_lds16(const void* g, void* l) {
  __builtin_amdgcn_global_load_lds(
      (const __attribute__((address_space(1))) void*)g,
      (__attribute__((address_space(3))) void*)l, 16, 0, 0);
}

// ---------------------------------------------------------------------------
// Prep: weight_logits [O][I][2] (mag,sgn interleaved) -> bf16 W_mean, W_var
// ---------------------------------------------------------------------------
__global__ void wprep_kernel(const float* __restrict__ wl,
                             unsigned short* __restrict__ wm,
                             unsigned short* __restrict__ wv) {
  int i = blockIdx.x * blockDim.x + threadIdx.x;       // 0 .. 524287 (2 elems each)
  f32x4 v = *reinterpret_cast<const f32x4*>(wl + (size_t)i * 4);
  float pm0 = 1.f / (1.f + expf(-v.x));
  float ps0 = 1.f / (1.f + expf(-v.y));
  float pm1 = 1.f / (1.f + expf(-v.z));
  float ps1 = 1.f / (1.f + expf(-v.w));
  float m0 = pm0 * (2.f * ps0 - 1.f);
  float m1 = pm1 * (2.f * ps1 - 1.f);
  float q0 = pm0 - m0 * m0;      // p_mag - (p_mag*s)^2  >= 0
  float q1 = pm1 - m1 * m1;
  us2 am = {f2bf(m0), f2bf(m1)};
  us2 av = {f2bf(q0), f2bf(q1)};
  *reinterpret_cast<us2*>(wm + (size_t)i * 2) = am;
  *reinterpret_cast<us2*>(wv + (size_t)i * 2) = av;
}

// ---------------------------------------------------------------------------
// Dual GEMM + fused epilogue
//   out[n][o] = (x@Wm^T + sqrt((x^2)@Wv^T) * noise) * scale + shift
// ---------------------------------------------------------------------------
__global__ __launch_bounds__(256, 2) void ternary_gemm(
    const float* __restrict__ x,
    const unsigned short* __restrict__ wm,
    const unsigned short* __restrict__ wv,
    const float* __restrict__ scale,
    const float* __restrict__ shift,
    const float* __restrict__ noise,
    float* __restrict__ out) {
  // 4 x 16KB LDS tiles, all XOR-swizzled: byte = row*128 + (kb ^ ((row&7)<<4))
  __shared__ alignas(16) unsigned short AsX[BM * BK];
  __shared__ alignas(16) unsigned short AsX2[BM * BK];
  __shared__ alignas(16) unsigned short BsM[BN * BK];
  __shared__ alignas(16) unsigned short BsV[BN * BK];

  const int tid  = threadIdx.x;
  const int lane = tid & 63;
  const int w    = tid >> 6;
  const int wr   = w >> 1;          // wave row (0..1)
  const int wc   = w & 1;           // wave col (0..1)
  const int l15  = lane & 15;
  const int l4   = lane >> 4;

  // XCD-bijective swizzle (2048 blocks % 8 == 0): each XCD gets a contiguous
  // chunk; bn-inner so x row-panels are reused within one XCD's L2.
  const int bid = blockIdx.x;
  const int swz = (bid & 7) * 256 + (bid >> 3);
  const int bm  = swz >> 3;         // 0..255
  const int bn  = swz & 7;          // 0..7
  const int rowBase = bm * BM;
  const int colBase = bn * BN;

  f32x4 accM[4][4];
  f32x4 accV[4][4];
#pragma unroll
  for (int i = 0; i < 4; ++i)
#pragma unroll
    for (int j = 0; j < 4; ++j) { accM[i][j] = (f32x4)0.f; accV[i][j] = (f32x4)0.f; }

  for (int kt = 0; kt < NKT; ++kt) {
    const int k0 = kt * BK;

    // ---- B staging: global_load_lds (linear LDS dest, inverse-swizzled src)
#pragma unroll
    for (int r = 0; r < 4; ++r) {
      int issue = w * 4 + r;                 // 0..15
      int slot  = issue * 64 + lane;         // 0..1023 (16B slots)
      int row   = slot >> 3;                 // 0..127 (output col within tile)
      int j     = slot & 7;                  // 16B chunk within row
      int ke    = (j ^ (row & 7)) << 3;      // element offset (pre-swizzle)
      size_t goff = (size_t)(colBase + row) * KDIM + k0 + ke;
      gl_lds16(wm + goff, (char*)BsM + issue * 1024);
      gl_lds16(wv + goff, (char*)BsV + issue * 1024);
    }

    // ---- A staging: f32 x -> bf16 x and bf16 x^2, swizzled ds_write
    const float* xb = x + (size_t)rowBase * KDIM + k0;
#pragma unroll
    for (int jj = 0; jj < 8; ++jj) {
      int flat = jj * 256 + tid;             // 0..2047 float4s
      int r    = flat >> 4;                  // row 0..127 (16 float4 per row)
      int c4   = flat & 15;
      f32x4 vx = *reinterpret_cast<const f32x4*>(xb + (size_t)r * KDIM + c4 * 4);
      us4 bx  = {f2bf(vx.x), f2bf(vx.y), f2bf(vx.z), f2bf(vx.w)};
      us4 bx2 = {f2bf(vx.x * vx.x), f2bf(vx.y * vx.y),
                 f2bf(vx.z * vx.z), f2bf(vx.w * vx.w)};
      int off = r * 128 + ((c4 * 8) ^ ((r & 7) << 4));
      *reinterpret_cast<us4*>((char*)AsX + off)  = bx;
      *reinterpret_cast<us4*>((char*)AsX2 + off) = bx2;
    }

    __syncthreads();   // drains vmcnt (global_load_lds) + lgkm, then barrier

    // ---- compute: 2 k-steps of 32, 4x4 frags, dual accumulate
#pragma unroll
    for (int ks = 0; ks < 2; ++ks) {
      us8 ax[4], ax2[4], bmf[4], bvf[4];
      const int kb = ks * 64 + (l4 << 4);    // byte offset of this lane's k-chunk
#pragma unroll
      for (int am = 0; am < 4; ++am) {
        int row = wr * 64 + am * 16 + l15;
        int off = row * 128 + (kb ^ ((row & 7) << 4));
        ax[am]  = *reinterpret_cast<const us8*>((const char*)AsX + off);
        ax2[am] = *reinterpret_cast<const us8*>((const char*)AsX2 + off);
      }
#pragma unroll
      for (int b = 0; b < 4; ++b) {
        int row = wc * 64 + b * 16 + l15;
        int off = row * 128 + (kb ^ ((row & 7) << 4));
        bmf[b] = *reinterpret_cast<const us8*>((const char*)BsM + off);
        bvf[b] = *reinterpret_cast<const us8*>((const char*)BsV + off);
      }
#pragma unroll
      for (int am = 0; am < 4; ++am)
#pragma unroll
        for (int b = 0; b < 4; ++b) {
          accM[am][b] = mfma16(ax[am],  bmf[b], accM[am][b]);
          accV[am][b] = mfma16(ax2[am], bvf[b], accV[am][b]);
        }
    }
    __syncthreads();
  }

  // ---- fused epilogue (C/D layout: col = lane&15, row = (lane>>4)*4 + reg)
#pragma unroll
  for (int am = 0; am < 4; ++am) {
    int row0 = rowBase + wr * 64 + am * 16 + (l4 << 2);
#pragma unroll
    for (int b = 0; b < 4; ++b) {
      int col = colBase + wc * 64 + b * 16 + l15;
      float sc = scale[col];
      float sh = shift[col];
#pragma unroll
      for (int j = 0; j < 4; ++j) {
        size_t idx = (size_t)(row0 + j) * ODIM + col;
        float nm = accM[am][b][j];
        float nv = accV[am][b][j];
        float nz = noise[idx];
        out[idx] = fmaf(nm + sqrtf(fmaxf(nv, 0.f)) * nz, sc, sh);
      }
    }
  }
}

// ---------------------------------------------------------------------------
extern "C" void kernel_launch(void* const* d_in, const int* in_sizes, int n_in,
                              void* d_out, int out_size, void* d_ws, size_t ws_size,
                              hipStream_t stream) {
  const float* x     = (const float*)d_in[0];   // [32768,1024]
  const float* wl    = (const float*)d_in[1];   // [1024,1024,2]
  const float* scale = (const float*)d_in[2];   // [1024]
  const float* shift = (const float*)d_in[3];   // [1024]
  const float* noise = (const float*)d_in[4];   // [32768,1024]
  float* out = (float*)d_out;

  unsigned short* wm = (unsigned short*)d_ws;            // [1024][1024] bf16
  unsigned short* wv = wm + (size_t)ODIM * KDIM;         // [1024][1024] bf16

  // 1M weight elements, 2 per thread
  wprep_kernel<<<(ODIM * KDIM / 2) / 256, 256, 0, stream>>>(wl, wm, wv);

  // grid = (32768/128) * (1024/128) = 2048 blocks
  ternary_gemm<<<(N_TOK / BM) * (ODIM / BN), 256, 0, stream>>>(
      x, wm, wv, scale, shift, noise, out);
}

// Round 2
// 218.331 us; speedup vs baseline: 1.0619x; 1.0619x over previous
//
#include <hip/hip_runtime.h>
#include <hip/hip_bf16.h>
#include <cmath>

// Problem constants (from reference)
#define N_TOK 32768
#define KDIM  1024
#define ODIM  1024

// GEMM tile config: 128x128 block, BK=64, 4 waves (2x2), wave tile 64x64 dual
#define BM 128
#define BN 128
#define BK 64
#define NKT (KDIM / BK)   // 16 k-tiles

typedef float          f32x4  __attribute__((ext_vector_type(4)));
typedef __bf16         bf16x8 __attribute__((ext_vector_type(8)));
typedef unsigned short us8    __attribute__((ext_vector_type(8)));
typedef unsigned short us4    __attribute__((ext_vector_type(4)));
typedef unsigned short us2    __attribute__((ext_vector_type(2)));

// round-to-nearest-even f32 -> bf16 (inputs are finite, no NaN handling needed)
static __device__ __forceinline__ unsigned short f2bf(float f) {
  unsigned u = __builtin_bit_cast(unsigned, f);
  u += 0x7FFFu + ((u >> 16) & 1u);
  return (unsigned short)(u >> 16);
}

static __device__ __forceinline__ f32x4 mfma16(us8 a, us8 b, f32x4 c) {
  return __builtin_amdgcn_mfma_f32_16x16x32_bf16(
      __builtin_bit_cast(bf16x8, a), __builtin_bit_cast(bf16x8, b), c, 0, 0, 0);
}

static __device__ __forceinline__ void gl_lds16(const void* g, void* l) {
  __builtin_amdgcn_global_load_lds(
      (const __attribute__((address_space(1))) void*)g,
      (__attribute__((address_space(3))) void*)l, 16, 0, 0);
}

// ---------------------------------------------------------------------------
// Prep: weight_logits [O][I][2] (mag,sgn interleaved) -> bf16 W_mean, W_var
// ---------------------------------------------------------------------------
__global__ void wprep_kernel(const float* __restrict__ wl,
                             unsigned short* __restrict__ wm,
                             unsigned short* __restrict__ wv) {
  int i = blockIdx.x * blockDim.x + threadIdx.x;       // 0 .. 524287 (2 elems each)
  f32x4 v = *reinterpret_cast<const f32x4*>(wl + (size_t)i * 4);
  float pm0 = 1.f / (1.f + expf(-v.x));
  float ps0 = 1.f / (1.f + expf(-v.y));
  float pm1 = 1.f / (1.f + expf(-v.z));
  float ps1 = 1.f / (1.f + expf(-v.w));
  float m0 = pm0 * (2.f * ps0 - 1.f);
  float m1 = pm1 * (2.f * ps1 - 1.f);
  float q0 = pm0 - m0 * m0;      // p_mag - (p_mag*s)^2  >= 0
  float q1 = pm1 - m1 * m1;
  us2 am = {f2bf(m0), f2bf(m1)};
  us2 av = {f2bf(q0), f2bf(q1)};
  *reinterpret_cast<us2*>(wm + (size_t)i * 2) = am;
  *reinterpret_cast<us2*>(wv + (size_t)i * 2) = av;
}

// ---------------------------------------------------------------------------
// Dual GEMM + fused epilogue
//   out[n][o] = (x@Wm^T + sqrt((x^2)@Wv^T) * noise) * scale + shift
// Pipeline per k-tile:
//   [barrier2 of prev iter ended: A/B LDS free, A(kt) f32 already in regs]
//   issue gl_lds B(kt)              (latency covered by A convert phase)
//   convert A(kt) regs -> ds_write
//   barrier1 (drains B DMA + A writes)
//   issue A(kt+1) f32 -> regs       (latency covered by full compute phase)
//   compute(kt)
//   barrier2 (drains A(kt+1) reg loads — already arrived)
// ---------------------------------------------------------------------------
__global__ __launch_bounds__(256, 2) void ternary_gemm(
    const float* __restrict__ x,
    const unsigned short* __restrict__ wm,
    const unsigned short* __restrict__ wv,
    const float* __restrict__ scale,
    const float* __restrict__ shift,
    const float* __restrict__ noise,
    float* __restrict__ out) {
  // 4 x 16KB LDS tiles, all XOR-swizzled: byte = row*128 + (kb ^ ((row&7)<<4))
  __shared__ alignas(16) unsigned short AsX[BM * BK];
  __shared__ alignas(16) unsigned short AsX2[BM * BK];
  __shared__ alignas(16) unsigned short BsM[BN * BK];
  __shared__ alignas(16) unsigned short BsV[BN * BK];

  const int tid  = threadIdx.x;
  const int lane = tid & 63;
  const int w    = tid >> 6;
  const int wr   = w >> 1;          // wave row (0..1)
  const int wc   = w & 1;           // wave col (0..1)
  const int l15  = lane & 15;
  const int l4   = lane >> 4;

  // XCD-bijective swizzle (2048 blocks % 8 == 0): each XCD gets a contiguous
  // chunk; bn-inner so x row-panels are reused within one XCD's L2.
  const int bid = blockIdx.x;
  const int swz = (bid & 7) * 256 + (bid >> 3);
  const int bm  = swz >> 3;         // 0..255
  const int bn  = swz & 7;          // 0..7
  const int rowBase = bm * BM;
  const int colBase = bn * BN;

  f32x4 accM[4][4];
  f32x4 accV[4][4];
#pragma unroll
  for (int i = 0; i < 4; ++i)
#pragma unroll
    for (int j = 0; j < 4; ++j) { accM[i][j] = (f32x4)0.f; accV[i][j] = (f32x4)0.f; }

  // Per-thread A-staging geometry (constant across k-tiles)
  const float* xbase = x + (size_t)rowBase * KDIM;

  // ---- prologue: prefetch A(0) into registers
  f32x4 apre[8];
#pragma unroll
  for (int jj = 0; jj < 8; ++jj) {
    int flat = jj * 256 + tid;             // 0..2047 float4s
    int r    = flat >> 4;                  // row 0..127
    int c4   = flat & 15;
    apre[jj] = *reinterpret_cast<const f32x4*>(xbase + (size_t)r * KDIM + c4 * 4);
  }

  for (int kt = 0; kt < NKT; ++kt) {
    const int k0 = kt * BK;

    // ---- B staging: global_load_lds (linear LDS dest, inverse-swizzled src)
    // Issued first; its L2 latency is covered by the A convert/ds_write below.
#pragma unroll
    for (int r = 0; r < 4; ++r) {
      int issue = w * 4 + r;                 // 0..15
      int slot  = issue * 64 + lane;         // 0..1023 (16B slots)
      int row   = slot >> 3;                 // 0..127 (output col within tile)
      int j     = slot & 7;                  // 16B chunk within row
      int ke    = (j ^ (row & 7)) << 3;      // element offset (pre-swizzle)
      size_t goff = (size_t)(colBase + row) * KDIM + k0 + ke;
      gl_lds16(wm + goff, (char*)BsM + issue * 1024);
      gl_lds16(wv + goff, (char*)BsV + issue * 1024);
    }

    // ---- A staging: convert prefetched regs -> bf16 x and x^2, swizzled write
#pragma unroll
    for (int jj = 0; jj < 8; ++jj) {
      int flat = jj * 256 + tid;
      int r    = flat >> 4;
      int c4   = flat & 15;
      f32x4 vx = apre[jj];
      us4 bx  = {f2bf(vx.x), f2bf(vx.y), f2bf(vx.z), f2bf(vx.w)};
      us4 bx2 = {f2bf(vx.x * vx.x), f2bf(vx.y * vx.y),
                 f2bf(vx.z * vx.z), f2bf(vx.w * vx.w)};
      int off = r * 128 + ((c4 * 8) ^ ((r & 7) << 4));
      *reinterpret_cast<us4*>((char*)AsX + off)  = bx;
      *reinterpret_cast<us4*>((char*)AsX2 + off) = bx2;
    }

    __syncthreads();   // barrier1: drains B DMA (vmcnt) + A ds_writes (lgkm)

    // ---- prefetch A(kt+1) into regs; flies during the whole compute phase
    if (kt + 1 < NKT) {
      const float* xnext = xbase + (kt + 1) * BK;
#pragma unroll
      for (int jj = 0; jj < 8; ++jj) {
        int flat = jj * 256 + tid;
        int r    = flat >> 4;
        int c4   = flat & 15;
        apre[jj] = *reinterpret_cast<const f32x4*>(xnext + (size_t)r * KDIM + c4 * 4);
      }
    }

    // ---- compute: 2 k-steps of 32, 4x4 frags, dual accumulate
#pragma unroll
    for (int ks = 0; ks < 2; ++ks) {
      us8 ax[4], ax2[4], bmf[4], bvf[4];
      const int kb = ks * 64 + (l4 << 4);    // byte offset of this lane's k-chunk
#pragma unroll
      for (int am = 0; am < 4; ++am) {
        int row = wr * 64 + am * 16 + l15;
        int off = row * 128 + (kb ^ ((row & 7) << 4));
        ax[am]  = *reinterpret_cast<const us8*>((const char*)AsX + off);
        ax2[am] = *reinterpret_cast<const us8*>((const char*)AsX2 + off);
      }
#pragma unroll
      for (int b = 0; b < 4; ++b) {
        int row = wc * 64 + b * 16 + l15;
        int off = row * 128 + (kb ^ ((row & 7) << 4));
        bmf[b] = *reinterpret_cast<const us8*>((const char*)BsM + off);
        bvf[b] = *reinterpret_cast<const us8*>((const char*)BsV + off);
      }
#pragma unroll
      for (int am = 0; am < 4; ++am)
#pragma unroll
        for (int b = 0; b < 4; ++b) {
          accM[am][b] = mfma16(ax[am],  bmf[b], accM[am][b]);
          accV[am][b] = mfma16(ax2[am], bvf[b], accV[am][b]);
        }
    }
    __syncthreads();   // barrier2: A(kt+1) reg loads drain here (already landed)
  }

  // ---- fused epilogue (C/D layout: col = lane&15, row = (lane>>4)*4 + reg)
#pragma unroll
  for (int am = 0; am < 4; ++am) {
    int row0 = rowBase + wr * 64 + am * 16 + (l4 << 2);
#pragma unroll
    for (int b = 0; b < 4; ++b) {
      int col = colBase + wc * 64 + b * 16 + l15;
      float sc = scale[col];
      float sh = shift[col];
#pragma unroll
      for (int j = 0; j < 4; ++j) {
        size_t idx = (size_t)(row0 + j) * ODIM + col;
        float nm = accM[am][b][j];
        float nv = accV[am][b][j];
        float nz = noise[idx];
        out[idx] = fmaf(nm + sqrtf(fmaxf(nv, 0.f)) * nz, sc, sh);
      }
    }
  }
}

// ---------------------------------------------------------------------------
extern "C" void kernel_launch(void* const* d_in, const int* in_sizes, int n_in,
                              void* d_out, int out_size, void* d_ws, size_t ws_size,
                              hipStream_t stream) {
  const float* x     = (const float*)d_in[0];   // [32768,1024]
  const float* wl    = (const float*)d_in[1];   // [1024,1024,2]
  const float* scale = (const float*)d_in[2];   // [1024]
  const float* shift = (const float*)d_in[3];   // [1024]
  const float* noise = (const float*)d_in[4];   // [32768,1024]
  float* out = (float*)d_out;

  unsigned short* wm = (unsigned short*)d_ws;            // [1024][1024] bf16
  unsigned short* wv = wm + (size_t)ODIM * KDIM;         // [1024][1024] bf16

  // 1M weight elements, 2 per thread
  wprep_kernel<<<(ODIM * KDIM / 2) / 256, 256, 0, stream>>>(wl, wm, wv);

  // grid = (32768/128) * (1024/128) = 2048 blocks
  ternary_gemm<<<(N_TOK / BM) * (ODIM / BN), 256, 0, stream>>>(
      x, wm, wv, scale, shift, noise, out);
}

// Round 3
// 207.910 us; speedup vs baseline: 1.1151x; 1.0501x over previous
//
#include <hip/hip_runtime.h>
#include <hip/hip_bf16.h>
#include <cmath>

// Problem constants (from reference)
#define N_TOK 32768
#define KDIM  1024
#define ODIM  1024

// GEMM tile: 128x128 block, BK=64, 8 waves duty-split:
//   waves 0-3: mean GEMM (x bf16 @ Wm), waves 4-7: var GEMM (x^2 bf16 @ Wv)
// Each wave: single-GEMM 64x64 tile, 4x4 frags of 16x16x32 -> acc = 64 VGPR.
#define BM 128
#define BN 128
#define BK 64
#define NKT (KDIM / BK)   // 16 k-tiles
#define THREADS 512

typedef float          f32x4  __attribute__((ext_vector_type(4)));
typedef __bf16         bf16x8 __attribute__((ext_vector_type(8)));
typedef __bf16         bf16x4 __attribute__((ext_vector_type(4)));
typedef unsigned short us8    __attribute__((ext_vector_type(8)));
typedef unsigned short us2    __attribute__((ext_vector_type(2)));

// round-to-nearest-even f32 -> bf16 (prep kernel only)
static __device__ __forceinline__ unsigned short f2bf(float f) {
  unsigned u = __builtin_bit_cast(unsigned, f);
  u += 0x7FFFu + ((u >> 16) & 1u);
  return (unsigned short)(u >> 16);
}

static __device__ __forceinline__ f32x4 mfma16(us8 a, us8 b, f32x4 c) {
  return __builtin_amdgcn_mfma_f32_16x16x32_bf16(
      __builtin_bit_cast(bf16x8, a), __builtin_bit_cast(bf16x8, b), c, 0, 0, 0);
}

static __device__ __forceinline__ void gl_lds16(const void* g, void* l) {
  __builtin_amdgcn_global_load_lds(
      (const __attribute__((address_space(1))) void*)g,
      (__attribute__((address_space(3))) void*)l, 16, 0, 0);
}

// ---------------------------------------------------------------------------
// Prep: weight_logits [O][I][2] (mag,sgn interleaved) -> bf16 W_mean, W_var
// ---------------------------------------------------------------------------
__global__ void wprep_kernel(const float* __restrict__ wl,
                             unsigned short* __restrict__ wm,
                             unsigned short* __restrict__ wv) {
  int i = blockIdx.x * blockDim.x + threadIdx.x;       // 2 elems each
  f32x4 v = *reinterpret_cast<const f32x4*>(wl + (size_t)i * 4);
  float pm0 = 1.f / (1.f + expf(-v.x));
  float ps0 = 1.f / (1.f + expf(-v.y));
  float pm1 = 1.f / (1.f + expf(-v.z));
  float ps1 = 1.f / (1.f + expf(-v.w));
  float m0 = pm0 * (2.f * ps0 - 1.f);
  float m1 = pm1 * (2.f * ps1 - 1.f);
  float q0 = pm0 - m0 * m0;
  float q1 = pm1 - m1 * m1;
  us2 am = {f2bf(m0), f2bf(m1)};
  us2 av = {f2bf(q0), f2bf(q1)};
  *reinterpret_cast<us2*>(wm + (size_t)i * 2) = am;
  *reinterpret_cast<us2*>(wv + (size_t)i * 2) = av;
}

// ---------------------------------------------------------------------------
// Duty-split dual GEMM + fused epilogue
// LDS: k-loop staging (4 x 16KB swizzled tiles, 64KB)
//      UNION epilogue exchange (Mex/Vex f32, stride 66, 67.6KB)
// ---------------------------------------------------------------------------
__global__ __launch_bounds__(THREADS, 4) void ternary_gemm(
    const float* __restrict__ x,
    const unsigned short* __restrict__ wm,
    const unsigned short* __restrict__ wv,
    const float* __restrict__ scale,
    const float* __restrict__ shift,
    const float* __restrict__ noise,
    float* __restrict__ out) {
  __shared__ alignas(16) char smem[67584];
  unsigned short* AsX  = (unsigned short*)smem;              // 16KB bf16 x
  unsigned short* AsX2 = (unsigned short*)(smem + 16384);    // 16KB bf16 x^2
  unsigned short* BsM  = (unsigned short*)(smem + 32768);    // 16KB bf16 Wm
  unsigned short* BsV  = (unsigned short*)(smem + 49152);    // 16KB bf16 Wv
  float* Mex = (float*)smem;          // [4 pairs][32 rows][66] f32 (rows 32-63 M)
  float* Vex = ((float*)smem) + 4 * 32 * 66;  // [4][32][66] f32 (rows 0-31 V)

  const int tid  = threadIdx.x;
  const int lane = tid & 63;
  const int w    = tid >> 6;        // 0..7
  const bool isVar = (w >= 4);
  const int p    = w & 3;           // wave pair id
  const int wr   = p >> 1;          // pair row (0..1)
  const int wc   = p & 1;           // pair col (0..1)
  const int l15  = lane & 15;
  const int l4   = lane >> 4;

  // XCD-bijective swizzle (2048 % 8 == 0), bn-inner for x L2 reuse per XCD
  const int bid = blockIdx.x;
  const int swz = (bid & 7) * 256 + (bid >> 3);
  const int bm  = swz >> 3;         // 0..255
  const int bn  = swz & 7;          // 0..7
  const int rowBase = bm * BM;
  const int colBase = bn * BN;

  f32x4 acc[4][4];
#pragma unroll
  for (int i = 0; i < 4; ++i)
#pragma unroll
    for (int j = 0; j < 4; ++j) acc[i][j] = (f32x4)0.f;

  const float* xbase = x + (size_t)rowBase * KDIM;

  // prologue: prefetch A(0) f32 into regs (4 float4 per thread)
  f32x4 apre[4];
#pragma unroll
  for (int jj = 0; jj < 4; ++jj) {
    int flat = jj * THREADS + tid;         // 0..2047
    int r    = flat >> 4;
    int c4   = flat & 15;
    apre[jj] = *reinterpret_cast<const f32x4*>(xbase + (size_t)r * KDIM + c4 * 4);
  }

  // wave-uniform duty pointers for the k-loop
  const char* Abase = isVar ? (const char*)AsX2 : (const char*)AsX;
  const char* Bbase = isVar ? (const char*)BsV  : (const char*)BsM;

  for (int kt = 0; kt < NKT; ++kt) {
    const int k0 = kt * BK;

    // ---- B staging: DMA both Wm and Wv tiles (inverse-swizzled global src)
#pragma unroll
    for (int r = 0; r < 2; ++r) {
      int slot = r * THREADS + tid;        // 0..1023 16B chunks
      int row  = slot >> 3;                // 0..127
      int j    = slot & 7;
      int ke   = (j ^ (row & 7)) << 3;
      size_t goff = (size_t)(colBase + row) * KDIM + k0 + ke;
      gl_lds16(wm + goff, (char*)BsM + slot * 16);
      gl_lds16(wv + goff, (char*)BsV + slot * 16);
    }

    // ---- A staging: convert prefetched f32 -> bf16 x and x^2, swizzled write
#pragma unroll
    for (int jj = 0; jj < 4; ++jj) {
      int flat = jj * THREADS + tid;
      int r    = flat >> 4;
      int c4   = flat & 15;
      f32x4 vx = apre[jj];
      bf16x4 bx  = {(__bf16)vx.x, (__bf16)vx.y, (__bf16)vx.z, (__bf16)vx.w};
      bf16x4 bx2 = {(__bf16)(vx.x * vx.x), (__bf16)(vx.y * vx.y),
                    (__bf16)(vx.z * vx.z), (__bf16)(vx.w * vx.w)};
      int off = r * 128 + ((c4 * 8) ^ ((r & 7) << 4));
      *reinterpret_cast<bf16x4*>((char*)AsX + off)  = bx;
      *reinterpret_cast<bf16x4*>((char*)AsX2 + off) = bx2;
    }

    __syncthreads();   // barrier1: drains B DMA (vmcnt) + A ds_writes (lgkm)

    // ---- prefetch A(kt+1); flies during compute
    if (kt + 1 < NKT) {
      const float* xnext = xbase + (kt + 1) * BK;
#pragma unroll
      for (int jj = 0; jj < 4; ++jj) {
        int flat = jj * THREADS + tid;
        int r    = flat >> 4;
        int c4   = flat & 15;
        apre[jj] = *reinterpret_cast<const f32x4*>(xnext + (size_t)r * KDIM + c4 * 4);
      }
    }

    // ---- compute: single GEMM per wave, 2 k-steps, 4x4 frags
#pragma unroll
    for (int ks = 0; ks < 2; ++ks) {
      us8 af[4], bf_[4];
      const int kb = ks * 64 + (l4 << 4);
#pragma unroll
      for (int am = 0; am < 4; ++am) {
        int row = wr * 64 + am * 16 + l15;
        int off = row * 128 + (kb ^ ((row & 7) << 4));
        af[am] = *reinterpret_cast<const us8*>(Abase + off);
      }
#pragma unroll
      for (int b = 0; b < 4; ++b) {
        int row = wc * 64 + b * 16 + l15;
        int off = row * 128 + (kb ^ ((row & 7) << 4));
        bf_[b] = *reinterpret_cast<const us8*>(Bbase + off);
      }
#pragma unroll
      for (int am = 0; am < 4; ++am)
#pragma unroll
        for (int b = 0; b < 4; ++b)
          acc[am][b] = mfma16(af[am], bf_[b], acc[am][b]);
    }
    __syncthreads();   // barrier2: staging LDS free for next tile
  }

  // ---- epilogue phase 1: cross-wave exchange through LDS (stride 66 f32)
  // mean wave ships M rows 32..63; var wave ships V rows 0..31.
  if (!isVar) {
#pragma unroll
    for (int am = 2; am < 4; ++am)
#pragma unroll
      for (int b = 0; b < 4; ++b)
#pragma unroll
        for (int j = 0; j < 4; ++j) {
          int lr = am * 16 + l4 * 4 + j;   // 32..63
          int lc = b * 16 + l15;
          Mex[(p * 32 + (lr - 32)) * 66 + lc] = acc[am][b][j];
        }
  } else {
#pragma unroll
    for (int am = 0; am < 2; ++am)
#pragma unroll
      for (int b = 0; b < 4; ++b)
#pragma unroll
        for (int j = 0; j < 4; ++j) {
          int lr = am * 16 + l4 * 4 + j;   // 0..31
          int lc = b * 16 + l15;
          Vex[(p * 32 + lr) * 66 + lc] = acc[am][b][j];
        }
  }
  __syncthreads();

  // ---- epilogue phase 2: each wave finishes half its pair-tile
  if (!isVar) {
    // rows 0..31: M in regs (am 0,1), V from Vex
#pragma unroll
    for (int am = 0; am < 2; ++am)
#pragma unroll
      for (int b = 0; b < 4; ++b) {
        int col = colBase + wc * 64 + b * 16 + l15;
        float sc = scale[col];
        float sh = shift[col];
#pragma unroll
        for (int j = 0; j < 4; ++j) {
          int lr = am * 16 + l4 * 4 + j;
          float vv = Vex[(p * 32 + lr) * 66 + b * 16 + l15];
          size_t idx = (size_t)(rowBase + wr * 64 + lr) * ODIM + col;
          out[idx] = fmaf(acc[am][b][j] + sqrtf(fmaxf(vv, 0.f)) * noise[idx], sc, sh);
        }
      }
  } else {
    // rows 32..63: V in regs (am 2,3), M from Mex
#pragma unroll
    for (int am = 2; am < 4; ++am)
#pragma unroll
      for (int b = 0; b < 4; ++b) {
        int col = colBase + wc * 64 + b * 16 + l15;
        float sc = scale[col];
        float sh = shift[col];
#pragma unroll
        for (int j = 0; j < 4; ++j) {
          int lr = am * 16 + l4 * 4 + j;   // 32..63
          float mm = Mex[(p * 32 + (lr - 32)) * 66 + b * 16 + l15];
          size_t idx = (size_t)(rowBase + wr * 64 + lr) * ODIM + col;
          out[idx] = fmaf(mm + sqrtf(fmaxf(acc[am][b][j], 0.f)) * noise[idx], sc, sh);
        }
      }
  }
}

// ---------------------------------------------------------------------------
extern "C" void kernel_launch(void* const* d_in, const int* in_sizes, int n_in,
                              void* d_out, int out_size, void* d_ws, size_t ws_size,
                              hipStream_t stream) {
  const float* x     = (const float*)d_in[0];   // [32768,1024]
  const float* wl    = (const float*)d_in[1];   // [1024,1024,2]
  const float* scale = (const float*)d_in[2];   // [1024]
  const float* shift = (const float*)d_in[3];   // [1024]
  const float* noise = (const float*)d_in[4];   // [32768,1024]
  float* out = (float*)d_out;

  unsigned short* wm = (unsigned short*)d_ws;            // [1024][1024] bf16
  unsigned short* wv = wm + (size_t)ODIM * KDIM;         // [1024][1024] bf16

  wprep_kernel<<<(ODIM * KDIM / 2) / 256, 256, 0, stream>>>(wl, wm, wv);

  // grid = (32768/128) * (1024/128) = 2048 blocks of 512 threads
  ternary_gemm<<<(N_TOK / BM) * (ODIM / BN), THREADS, 0, stream>>>(
      x, wm, wv, scale, shift, noise, out);
}